// Round 3
// baseline (196.627 us; speedup 1.0000x reference)
//
#include <hip/hip_runtime.h>

#define Bb 2
#define Ll 1024
#define Dd 256
#define Ee 64
#define Tt 8

typedef float f4 __attribute__((ext_vector_type(4)));

// K1: fold output projection into per-type transforms.
// M1[t][e][d] = sum_m W[e][m]     * LT[t][m][d]
// M2[t][e][d] = sum_m W[e][256+m] * RT[t][m][d]
// grid = Tt*16 blocks: (t, group of 4 e). threads: ec = tid>>6 (which e), d4 = tid&63 (f4 col).
__global__ __launch_bounds__(256) void combine_kernel(const float* __restrict__ LT,
                                                      const float* __restrict__ RT,
                                                      const float* __restrict__ W,
                                                      float* __restrict__ M1,
                                                      float* __restrict__ M2) {
    int t  = blockIdx.x >> 4;
    int e0 = (blockIdx.x & 15) * 4;
    int tid = threadIdx.x;
    int ec = tid >> 6;
    int d4 = tid & 63;

    __shared__ float s_w1[4][Dd];
    __shared__ float s_w2[4][Dd];
    {   // stage 4 rows of W (each 512 floats) with f4 loads
        const f4* w4 = (const f4*)(W + e0 * 2 * Dd);   // 512 f4 total
        #pragma unroll
        for (int k = 0; k < 2; ++k) {
            int idx = tid + k * 256;
            f4 v = w4[idx];
            int row = idx >> 7;        // 128 f4 per W row
            int c   = idx & 127;
            if (c < 64) *((f4*)&s_w1[row][0] + c)        = v;
            else        *((f4*)&s_w2[row][0] + (c - 64)) = v;
        }
    }
    __syncthreads();

    const f4* lt4 = (const f4*)(LT + t * Dd * Dd) + d4;  // row stride = 64 f4
    const f4* rt4 = (const f4*)(RT + t * Dd * Dd) + d4;
    f4 a1 = {0.f, 0.f, 0.f, 0.f}, a2 = {0.f, 0.f, 0.f, 0.f};
    #pragma unroll 8
    for (int m = 0; m < Dd; ++m) {
        f4 lv = lt4[m * 64];          // 1 KB/wave, L1-broadcast across the 4 waves
        f4 rv = rt4[m * 64];
        a1 += s_w1[ec][m] * lv;
        a2 += s_w2[ec][m] * rv;
    }
    int e = e0 + ec;
    ((f4*)(M1 + (t * Ee + e) * Dd))[d4] = a1;
    ((f4*)(M2 + (t * Ee + e) * Dd))[d4] = a2;
}

// K2: lp[b][l][e] = sum_d M1[t][e][d]*emb[b][l][d], rp likewise with M2. t = types[b][l].
__global__ __launch_bounds__(256) void proj_kernel(const float* __restrict__ emb,
                                                   const int* __restrict__ types,
                                                   const float* __restrict__ M1,
                                                   const float* __restrict__ M2,
                                                   float* __restrict__ lp,
                                                   float* __restrict__ rp) {
    int bl = blockIdx.x;       // grid = B*L
    int tid = threadIdx.x;     // e = tid&63, chunk = tid>>6 (quarter of d)
    __shared__ float s_e[Dd];
    s_e[tid] = emb[bl * Dd + tid];
    __syncthreads();
    int t = types[bl];
    int e = tid & 63;
    int chunk = tid >> 6;
    const f4* m1 = (const f4*)(M1 + (t * Ee + e) * Dd + chunk * 64);
    const f4* m2 = (const f4*)(M2 + (t * Ee + e) * Dd + chunk * 64);
    const f4* se = (const f4*)(s_e + chunk * 64);   // wave-uniform -> LDS broadcast
    f4 a1 = {0.f,0.f,0.f,0.f}, a2 = {0.f,0.f,0.f,0.f};
    #pragma unroll
    for (int i = 0; i < 16; ++i) {
        f4 sv = se[i];
        a1 += m1[i] * sv;
        a2 += m2[i] * sv;
    }
    __shared__ float r1[256], r2[256];
    r1[tid] = a1.x + a1.y + a1.z + a1.w;
    r2[tid] = a2.x + a2.y + a2.z + a2.w;
    __syncthreads();
    if (tid < 64) {
        lp[bl * Ee + tid] = r1[tid] + r1[tid + 64] + r1[tid + 128] + r1[tid + 192];
        rp[bl * Ee + tid] = r2[tid] + r2[tid + 64] + r2[tid + 128] + r2[tid + 192];
    }
}

// K3 (the bulk): out[b][l][m][e] = lp[b][l][e] + rp[b][m][e] + bias[e]
// grid = 512 blocks: (b, l-tile of 16, m-tile of 256). All operands staged in LDS
// once (68 KB), then a pure coalesced store stream (1 MB/block).
__global__ __launch_bounds__(256) void bcast_kernel(const float* __restrict__ lp,
                                                    const float* __restrict__ rp,
                                                    const float* __restrict__ bias,
                                                    f4* __restrict__ out) {
    int blk = blockIdx.x;
    int mt = blk & 3;              // which 256-m tile
    int lt = (blk >> 2) & 63;      // which 16-l tile
    int b  = blk >> 8;
    int tid = threadIdx.x;

    __shared__ f4 s_rp[256 * 16];  // 64 KB: rp tile (+0 conflict: linear copy)
    __shared__ f4 s_lp[16 * 16];   // 4 KB: lp rows + bias

    const f4* rp4 = (const f4*)(rp + (b * Ll + mt * 256) * Ee);
    #pragma unroll
    for (int k = 0; k < 16; ++k)
        s_rp[tid + k * 256] = rp4[tid + k * 256];
    {
        int l_ = tid >> 4, e4 = tid & 15;
        const f4* lp4 = (const f4*)(lp + (b * Ll + lt * 16 + l_) * Ee);
        const f4* b4  = (const f4*)bias;
        s_lp[tid] = lp4[e4] + b4[e4];
    }
    __syncthreads();

    int e4 = tid & 15;             // f4 within e-dim
    int ml = tid >> 4;             // 16 m per inner pass
    size_t base = ((size_t)(b * Ll + lt * 16) * Ll + mt * 256) * (Ee / 4);
    for (int l = 0; l < 16; ++l) {
        f4 lv = s_lp[l * 16 + e4];
        f4* o = out + base + (size_t)l * (Ll * Ee / 4);
        #pragma unroll
        for (int mc = 0; mc < 16; ++mc) {
            int m = mc * 16 + ml;
            o[m * 16 + e4] = lv + s_rp[m * 16 + e4];   // 1 KB contiguous per wave
        }
    }
}

extern "C" void kernel_launch(void* const* d_in, const int* in_sizes, int n_in,
                              void* d_out, int out_size, void* d_ws, size_t ws_size,
                              hipStream_t stream) {
    const float* emb   = (const float*)d_in[0];  // (B,L,D)
    const int*   types = (const int*)d_in[1];    // (B,L)
    const float* LT    = (const float*)d_in[2];  // (T,D,D)
    const float* RT    = (const float*)d_in[3];  // (T,D,D)
    const float* W     = (const float*)d_in[4];  // (E,2D)
    const float* bias  = (const float*)d_in[5];  // (E,)

    float* ws = (float*)d_ws;
    float* M1 = ws;                       // T*E*D = 131072 floats
    float* M2 = M1 + Tt * Ee * Dd;        // 131072
    float* lp = M2 + Tt * Ee * Dd;        // B*L*E = 131072
    float* rp = lp + Bb * Ll * Ee;        // 131072   (total 2 MiB)

    combine_kernel<<<Tt * 16, 256, 0, stream>>>(LT, RT, W, M1, M2);
    proj_kernel<<<Bb * Ll, 256, 0, stream>>>(emb, types, M1, M2, lp, rp);
    bcast_kernel<<<512, 256, 0, stream>>>(lp, rp, bias, (f4*)d_out);
}

// Round 4
// 160.716 us; speedup vs baseline: 1.2234x; 1.2234x over previous
//
#include <hip/hip_runtime.h>

#define Bb 2
#define Ll 1024
#define Dd 256
#define Ee 64
#define Tt 8

typedef float f4 __attribute__((ext_vector_type(4)));

// K1: fold output projection into per-type transforms, stored TRANSPOSED:
// M1t[t][d][e] = sum_m W[e][m]     * LT[t][m][d]
// M2t[t][d][e] = sum_m W[e][256+m] * RT[t][m][d]
// grid = Tt*16 blocks: (t, group of 4 e). threads: ec = tid>>6, d4 = tid&63.
__global__ __launch_bounds__(256) void combine_kernel(const float* __restrict__ LT,
                                                      const float* __restrict__ RT,
                                                      const float* __restrict__ W,
                                                      float* __restrict__ M1t,
                                                      float* __restrict__ M2t) {
    int t  = blockIdx.x >> 4;
    int e0 = (blockIdx.x & 15) * 4;
    int tid = threadIdx.x;
    int ec = tid >> 6;
    int d4 = tid & 63;

    __shared__ float s_w1[4][Dd];
    __shared__ float s_w2[4][Dd];
    {   // stage 4 rows of W (each 512 floats) with f4 loads
        const f4* w4 = (const f4*)(W + e0 * 2 * Dd);   // 512 f4 total
        #pragma unroll
        for (int k = 0; k < 2; ++k) {
            int idx = tid + k * 256;
            f4 v = w4[idx];
            int row = idx >> 7;        // 128 f4 per W row
            int c   = idx & 127;
            if (c < 64) *((f4*)&s_w1[row][0] + c)        = v;
            else        *((f4*)&s_w2[row][0] + (c - 64)) = v;
        }
    }
    __syncthreads();

    const f4* lt4 = (const f4*)(LT + t * Dd * Dd) + d4;  // row stride = 64 f4
    const f4* rt4 = (const f4*)(RT + t * Dd * Dd) + d4;
    f4 a1 = {0.f, 0.f, 0.f, 0.f}, a2 = {0.f, 0.f, 0.f, 0.f};
    #pragma unroll 8
    for (int m = 0; m < Dd; ++m) {
        f4 lv = lt4[m * 64];          // 1 KB/wave coalesced
        f4 rv = rt4[m * 64];
        a1 += s_w1[ec][m] * lv;
        a2 += s_w2[ec][m] * rv;
    }
    int e = e0 + ec;
    // transposed scatter store: 2 MB total into L2-resident ws — cheap
    #pragma unroll
    for (int j = 0; j < 4; ++j) {
        M1t[(t * Dd + d4 * 4 + j) * Ee + e] = a1[j];
        M2t[(t * Dd + d4 * 4 + j) * Ee + e] = a2[j];
    }
}

// K2: lp[b][l][e] = sum_d M1t[t][d][e]*emb[b][l][d], rp likewise. t = types[b][l].
// Lanes = consecutive e -> every M-load is 256B coalesced.
__global__ __launch_bounds__(256) void proj_kernel(const float* __restrict__ emb,
                                                   const int* __restrict__ types,
                                                   const float* __restrict__ M1t,
                                                   const float* __restrict__ M2t,
                                                   float* __restrict__ lp,
                                                   float* __restrict__ rp) {
    int bl = blockIdx.x;       // grid = B*L
    int tid = threadIdx.x;     // e = tid&63, chunk = tid>>6 (quarter of d)
    __shared__ float s_e[Dd];
    s_e[tid] = emb[bl * Dd + tid];
    __syncthreads();
    int t = types[bl];
    int e = tid & 63;
    int chunk = tid >> 6;
    const float* m1 = M1t + (size_t)t * Dd * Ee + e;
    const float* m2 = M2t + (size_t)t * Dd * Ee + e;
    float a1 = 0.f, a2 = 0.f;
    #pragma unroll 8
    for (int dd = 0; dd < 64; ++dd) {
        int d = chunk * 64 + dd;
        float s = s_e[d];               // wave-uniform -> LDS broadcast
        a1 = fmaf(m1[d * Ee], s, a1);   // 256B coalesced across lanes
        a2 = fmaf(m2[d * Ee], s, a2);
    }
    __shared__ float r1[256], r2[256];
    r1[tid] = a1;
    r2[tid] = a2;
    __syncthreads();
    if (tid < 64) {
        lp[bl * Ee + tid] = r1[tid] + r1[tid + 64] + r1[tid + 128] + r1[tid + 192];
        rp[bl * Ee + tid] = r2[tid] + r2[tid + 64] + r2[tid + 128] + r2[tid + 192];
    }
}

// K3 (the bulk): out[b][l][m][e] = lp[b][l][e] + rp[b][m][e] + bias[e]
// grid = B*L*4 = 8192 blocks: (b, l, m-quarter). No LDS, no barrier, plain
// stores. All 16 rp loads issued into registers up front, then 16 contiguous
// 1KB/wave stores.
__global__ __launch_bounds__(256) void bcast_kernel(const float* __restrict__ lp,
                                                    const float* __restrict__ rp,
                                                    const float* __restrict__ bias,
                                                    f4* __restrict__ out) {
    int blk = blockIdx.x;
    int q  = blk & 3;              // m-quarter (256 m values)
    int bl = blk >> 2;             // (b,l)
    int b  = bl >> 10;
    int tid = threadIdx.x;
    int e4 = tid & 15;             // f4 within e-dim
    int ml = tid >> 4;             // 16 m per pass

    const f4* lp4 = (const f4*)lp;
    const f4* b4  = (const f4*)bias;
    f4 lv = lp4[bl * 16 + e4] + b4[e4];   // one 256B line, wave-broadcast

    const f4* rp4 = (const f4*)(rp + ((size_t)b * Ll + q * 256) * Ee);
    f4* o = out + ((size_t)bl * Ll + q * 256) * (Ee / 4);

    f4 rv[16];
    #pragma unroll
    for (int mc = 0; mc < 16; ++mc)        // issue all loads first (L2-resident)
        rv[mc] = rp4[(mc * 16 + ml) * 16 + e4];
    #pragma unroll
    for (int mc = 0; mc < 16; ++mc)        // pure coalesced store stream
        o[(mc * 16 + ml) * 16 + e4] = lv + rv[mc];
}

extern "C" void kernel_launch(void* const* d_in, const int* in_sizes, int n_in,
                              void* d_out, int out_size, void* d_ws, size_t ws_size,
                              hipStream_t stream) {
    const float* emb   = (const float*)d_in[0];  // (B,L,D)
    const int*   types = (const int*)d_in[1];    // (B,L)
    const float* LT    = (const float*)d_in[2];  // (T,D,D)
    const float* RT    = (const float*)d_in[3];  // (T,D,D)
    const float* W     = (const float*)d_in[4];  // (E,2D)
    const float* bias  = (const float*)d_in[5];  // (E,)

    float* ws = (float*)d_ws;
    float* M1t = ws;                      // T*D*E = 131072 floats
    float* M2t = M1t + Tt * Dd * Ee;      // 131072
    float* lp  = M2t + Tt * Dd * Ee;      // B*L*E = 131072
    float* rp  = lp + Bb * Ll * Ee;       // 131072   (total 2 MiB)

    combine_kernel<<<Tt * 16, 256, 0, stream>>>(LT, RT, W, M1t, M2t);
    proj_kernel<<<Bb * Ll, 256, 0, stream>>>(emb, types, M1t, M2t, lp, rp);
    bcast_kernel<<<Bb * Ll * 4, 256, 0, stream>>>(lp, rp, bias, (f4*)d_out);
}

// Round 5
// 146.485 us; speedup vs baseline: 1.3423x; 1.0972x over previous
//
#include <hip/hip_runtime.h>

#define Bb 2
#define Ll 1024
#define Dd 256
#define Ee 64
#define Tt 8

typedef float f4 __attribute__((ext_vector_type(4)));

// K1: fold output projection into per-type transforms, stored TRANSPOSED:
// M1t[t][d][e] = sum_m W[e][m]     * LT[t][m][d]
// M2t[t][d][e] = sum_m W[e][256+m] * RT[t][m][d]
__global__ __launch_bounds__(256) void combine_kernel(const float* __restrict__ LT,
                                                      const float* __restrict__ RT,
                                                      const float* __restrict__ W,
                                                      float* __restrict__ M1t,
                                                      float* __restrict__ M2t) {
    int t  = blockIdx.x >> 4;
    int e0 = (blockIdx.x & 15) * 4;
    int tid = threadIdx.x;
    int ec = tid >> 6;
    int d4 = tid & 63;

    __shared__ float s_w1[4][Dd];
    __shared__ float s_w2[4][Dd];
    {   // stage 4 rows of W (each 512 floats) with f4 loads
        const f4* w4 = (const f4*)(W + e0 * 2 * Dd);   // 512 f4 total
        #pragma unroll
        for (int k = 0; k < 2; ++k) {
            int idx = tid + k * 256;
            f4 v = w4[idx];
            int row = idx >> 7;        // 128 f4 per W row
            int c   = idx & 127;
            if (c < 64) *((f4*)&s_w1[row][0] + c)        = v;
            else        *((f4*)&s_w2[row][0] + (c - 64)) = v;
        }
    }
    __syncthreads();

    const f4* lt4 = (const f4*)(LT + t * Dd * Dd) + d4;  // row stride = 64 f4
    const f4* rt4 = (const f4*)(RT + t * Dd * Dd) + d4;
    f4 a1 = {0.f, 0.f, 0.f, 0.f}, a2 = {0.f, 0.f, 0.f, 0.f};
    #pragma unroll 8
    for (int m = 0; m < Dd; ++m) {
        f4 lv = lt4[m * 64];          // 1 KB/wave coalesced
        f4 rv = rt4[m * 64];
        a1 += s_w1[ec][m] * lv;
        a2 += s_w2[ec][m] * rv;
    }
    int e = e0 + ec;
    // transposed scatter store: 2 MB total into L2-resident ws — cheap
    #pragma unroll
    for (int j = 0; j < 4; ++j) {
        M1t[(t * Dd + d4 * 4 + j) * Ee + e] = a1[j];
        M2t[(t * Dd + d4 * 4 + j) * Ee + e] = a2[j];
    }
}

// K2: lp[b][l][e] = sum_d M1t[t][d][e]*emb[b][l][d], rp likewise. t = types[b][l].
// Lanes = consecutive e -> every M-load is 256B coalesced.
__global__ __launch_bounds__(256) void proj_kernel(const float* __restrict__ emb,
                                                   const int* __restrict__ types,
                                                   const float* __restrict__ M1t,
                                                   const float* __restrict__ M2t,
                                                   float* __restrict__ lp,
                                                   float* __restrict__ rp) {
    int bl = blockIdx.x;       // grid = B*L
    int tid = threadIdx.x;     // e = tid&63, chunk = tid>>6 (quarter of d)
    __shared__ float s_e[Dd];
    s_e[tid] = emb[bl * Dd + tid];
    __syncthreads();
    int t = types[bl];
    int e = tid & 63;
    int chunk = tid >> 6;
    const float* m1 = M1t + (size_t)t * Dd * Ee + e;
    const float* m2 = M2t + (size_t)t * Dd * Ee + e;
    float a1 = 0.f, a2 = 0.f;
    #pragma unroll 8
    for (int dd = 0; dd < 64; ++dd) {
        int d = chunk * 64 + dd;
        float s = s_e[d];               // wave-uniform -> LDS broadcast
        a1 = fmaf(m1[d * Ee], s, a1);   // 256B coalesced across lanes
        a2 = fmaf(m2[d * Ee], s, a2);
    }
    __shared__ float r1[256], r2[256];
    r1[tid] = a1;
    r2[tid] = a2;
    __syncthreads();
    if (tid < 64) {
        lp[bl * Ee + tid] = r1[tid] + r1[tid + 64] + r1[tid + 128] + r1[tid + 192];
        rp[bl * Ee + tid] = r2[tid] + r2[tid + 64] + r2[tid + 128] + r2[tid + 192];
    }
}

// K3 (the bulk): out[b][l][m][e] = lp[b][l][e] + rp[b][m][e] + bias[e]
// grid = B * 256 l-quads * 4 m-quarters = 2048 blocks. Per thread: 16 rp
// loads (held in regs), 4 lp loads, then 64 independent NONTEMPORAL stores
// (nt keeps the 536MB output stream from evicting rp out of L2).
__global__ __launch_bounds__(256) void bcast_kernel(const float* __restrict__ lp,
                                                    const float* __restrict__ rp,
                                                    const float* __restrict__ bias,
                                                    f4* __restrict__ out) {
    int blk = blockIdx.x;
    int q  = blk & 3;              // m-quarter (256 m values)
    int lg = (blk >> 2) & 255;     // l-quad
    int b  = blk >> 10;
    int tid = threadIdx.x;
    int e4 = tid & 15;             // f4 within e-dim
    int ml = tid >> 4;             // 16 m slots per pass

    const f4* rp4 = (const f4*)(rp + ((size_t)b * Ll + q * 256) * Ee);
    f4 rv[16];
    #pragma unroll
    for (int mc = 0; mc < 16; ++mc)        // rp quarter -> 64 VGPRs (L2-hot)
        rv[mc] = rp4[(mc * 16 + ml) * 16 + e4];

    const f4* lp4 = (const f4*)lp;
    const f4* b4  = (const f4*)bias;
    f4 bb = b4[e4];
    int l0 = lg * 4;
    #pragma unroll
    for (int li = 0; li < 4; ++li) {
        int l = l0 + li;
        f4 lv = lp4[((size_t)b * Ll + l) * 16 + e4] + bb;
        f4* o = out + (((size_t)b * Ll + l) * Ll + q * 256) * 16;
        #pragma unroll
        for (int mc = 0; mc < 16; ++mc)    // 4KB contiguous per block per mc
            __builtin_nontemporal_store(lv + rv[mc], &o[(mc * 16 + ml) * 16 + e4]);
    }
}

extern "C" void kernel_launch(void* const* d_in, const int* in_sizes, int n_in,
                              void* d_out, int out_size, void* d_ws, size_t ws_size,
                              hipStream_t stream) {
    const float* emb   = (const float*)d_in[0];  // (B,L,D)
    const int*   types = (const int*)d_in[1];    // (B,L)
    const float* LT    = (const float*)d_in[2];  // (T,D,D)
    const float* RT    = (const float*)d_in[3];  // (T,D,D)
    const float* W     = (const float*)d_in[4];  // (E,2D)
    const float* bias  = (const float*)d_in[5];  // (E,)

    float* ws = (float*)d_ws;
    float* M1t = ws;                      // T*D*E = 131072 floats
    float* M2t = M1t + Tt * Dd * Ee;      // 131072
    float* lp  = M2t + Tt * Dd * Ee;      // B*L*E = 131072
    float* rp  = lp + Bb * Ll * Ee;       // 131072   (total 2 MiB)

    combine_kernel<<<Tt * 16, 256, 0, stream>>>(LT, RT, W, M1t, M2t);
    proj_kernel<<<Bb * Ll, 256, 0, stream>>>(emb, types, M1t, M2t, lp, rp);
    bcast_kernel<<<Bb * 256 * 4, 256, 0, stream>>>(lp, rp, bias, (f4*)d_out);
}

// Round 6
// 143.248 us; speedup vs baseline: 1.3726x; 1.0226x over previous
//
#include <hip/hip_runtime.h>

#define Bb 2
#define Ll 1024
#define Dd 256
#define Ee 64
#define Tt 8

typedef float f4 __attribute__((ext_vector_type(4)));

// K1: fold output projection into per-type transforms, stored TRANSPOSED:
// M1t[t][d][e] = sum_m W[e][m]     * LT[t][m][d]
// M2t[t][d][e] = sum_m W[e][256+m] * RT[t][m][d]
// grid = Tt*32 = 256 blocks (t, pair of e), 128 threads: ec=tid>>6, d4=tid&63.
__global__ __launch_bounds__(128) void combine_kernel(const float* __restrict__ LT,
                                                      const float* __restrict__ RT,
                                                      const float* __restrict__ W,
                                                      float* __restrict__ M1t,
                                                      float* __restrict__ M2t) {
    int t  = blockIdx.x >> 5;
    int e0 = (blockIdx.x & 31) * 2;
    int tid = threadIdx.x;
    int ec = tid >> 6;
    int d4 = tid & 63;

    __shared__ float s_w1[2][Dd];
    __shared__ float s_w2[2][Dd];
    {   // stage 2 rows of W (each 512 floats = 128 f4) with f4 loads
        const f4* w4 = (const f4*)(W + e0 * 2 * Dd);   // 256 f4 total
        #pragma unroll
        for (int k = 0; k < 2; ++k) {
            int idx = tid + k * 128;
            f4 v = w4[idx];
            int row = idx >> 7;
            int c   = idx & 127;
            if (c < 64) *((f4*)&s_w1[row][0] + c)        = v;
            else        *((f4*)&s_w2[row][0] + (c - 64)) = v;
        }
    }
    __syncthreads();

    const f4* lt4 = (const f4*)(LT + t * Dd * Dd) + d4;  // row stride = 64 f4
    const f4* rt4 = (const f4*)(RT + t * Dd * Dd) + d4;
    f4 a1 = {0.f, 0.f, 0.f, 0.f}, a2 = {0.f, 0.f, 0.f, 0.f};
    #pragma unroll 8
    for (int m = 0; m < Dd; ++m) {
        f4 lv = lt4[m * 64];          // 1 KB/wave coalesced
        f4 rv = rt4[m * 64];
        a1 += s_w1[ec][m] * lv;
        a2 += s_w2[ec][m] * rv;
    }
    int e = e0 + ec;
    // transposed scatter store: 2 MB total into L2-resident ws — cheap
    #pragma unroll
    for (int j = 0; j < 4; ++j) {
        M1t[(t * Dd + d4 * 4 + j) * Ee + e] = a1[j];
        M2t[(t * Dd + d4 * 4 + j) * Ee + e] = a2[j];
    }
}

// K2: lp[b][l][e] = sum_d M1t[t][d][e]*emb[b][l][d], rp likewise. t = types[b][l].
// Lanes = consecutive e -> every M-load is 256B coalesced.
__global__ __launch_bounds__(256) void proj_kernel(const float* __restrict__ emb,
                                                   const int* __restrict__ types,
                                                   const float* __restrict__ M1t,
                                                   const float* __restrict__ M2t,
                                                   float* __restrict__ lp,
                                                   float* __restrict__ rp) {
    int bl = blockIdx.x;       // grid = B*L
    int tid = threadIdx.x;     // e = tid&63, chunk = tid>>6 (quarter of d)
    __shared__ float s_e[Dd];
    s_e[tid] = emb[bl * Dd + tid];
    __syncthreads();
    int t = types[bl];
    int e = tid & 63;
    int chunk = tid >> 6;
    const float* m1 = M1t + (size_t)t * Dd * Ee + e;
    const float* m2 = M2t + (size_t)t * Dd * Ee + e;
    float a1 = 0.f, a2 = 0.f;
    #pragma unroll 8
    for (int dd = 0; dd < 64; ++dd) {
        int d = chunk * 64 + dd;
        float s = s_e[d];               // wave-uniform -> LDS broadcast
        a1 = fmaf(m1[d * Ee], s, a1);   // 256B coalesced across lanes
        a2 = fmaf(m2[d * Ee], s, a2);
    }
    __shared__ float r1[256], r2[256];
    r1[tid] = a1;
    r2[tid] = a2;
    __syncthreads();
    if (tid < 64) {
        lp[bl * Ee + tid] = r1[tid] + r1[tid + 64] + r1[tid + 128] + r1[tid + 192];
        rp[bl * Ee + tid] = r2[tid] + r2[tid + 64] + r2[tid + 128] + r2[tid + 192];
    }
}

// K3 (the bulk): out[b][l][m][e] = lp[b][l][e] + rp[b][m][e] + bias[e]
// grid = 1024 blocks = b(2) x mchunk(16, 64 m each) x lrange(32, 32 l each).
// Per thread: 4 rp f4 (+bias) held in registers for the whole block, then a
// near-pure nt-store stream: per l, one 256B wave-broadcast lp load + 4 x 1KB
// coalesced nt stores. Load:store byte ratio 1:16. No LDS, no barriers.
__global__ __launch_bounds__(256) void bcast_kernel(const float* __restrict__ lp,
                                                    const float* __restrict__ rp,
                                                    const float* __restrict__ bias,
                                                    f4* __restrict__ out) {
    int blk = blockIdx.x;
    int lr = blk & 31;             // l-range (32 l values)
    int mc = (blk >> 5) & 15;      // m-chunk (64 m values)
    int b  = blk >> 9;
    int tid = threadIdx.x;
    int e4 = tid & 15;             // f4 within e-dim
    int ml = tid >> 4;             // m slot within 16

    const f4* rp4 = (const f4*)rp;
    const f4* lp4 = (const f4*)lp;
    f4 bb = ((const f4*)bias)[e4];

    f4 rv[4];
    #pragma unroll
    for (int k = 0; k < 4; ++k) {  // rp chunk + bias -> 16 VGPRs, kept all kernel
        int m = mc * 64 + k * 16 + ml;
        rv[k] = rp4[((size_t)b * Ll + m) * 16 + e4] + bb;
    }

    int l0 = lr * 32;
    #pragma unroll 4
    for (int li = 0; li < 32; ++li) {
        int l = l0 + li;
        f4 lv = lp4[((size_t)b * Ll + l) * 16 + e4];   // one 256B line/wave
        f4* o = out + (((size_t)b * Ll + l) * Ll + mc * 64) * 16;
        #pragma unroll
        for (int k = 0; k < 4; ++k) {
            int moff = k * 16 + ml;
            __builtin_nontemporal_store(lv + rv[k], &o[moff * 16 + e4]);
        }
    }
}

extern "C" void kernel_launch(void* const* d_in, const int* in_sizes, int n_in,
                              void* d_out, int out_size, void* d_ws, size_t ws_size,
                              hipStream_t stream) {
    const float* emb   = (const float*)d_in[0];  // (B,L,D)
    const int*   types = (const int*)d_in[1];    // (B,L)
    const float* LT    = (const float*)d_in[2];  // (T,D,D)
    const float* RT    = (const float*)d_in[3];  // (T,D,D)
    const float* W     = (const float*)d_in[4];  // (E,2D)
    const float* bias  = (const float*)d_in[5];  // (E,)

    float* ws = (float*)d_ws;
    float* M1t = ws;                      // T*D*E = 131072 floats
    float* M2t = M1t + Tt * Dd * Ee;      // 131072
    float* lp  = M2t + Tt * Dd * Ee;      // B*L*E = 131072
    float* rp  = lp + Bb * Ll * Ee;       // 131072   (total 2 MiB)

    combine_kernel<<<Tt * 32, 128, 0, stream>>>(LT, RT, W, M1t, M2t);
    proj_kernel<<<Bb * Ll, 256, 0, stream>>>(emb, types, M1t, M2t, lp, rp);
    bcast_kernel<<<Bb * 16 * 32, 256, 0, stream>>>(lp, rp, bias, (f4*)d_out);
}